// Round 6
// baseline (159.645 us; speedup 1.0000x reference)
//
#include <hip/hip_runtime.h>
#include <math.h>

#define N_NODES 8192
#define N_EDGES 262144
#define NFEAT 128
#define NHID 256
#define NCLASS 16

// ws layout (bytes):
//   deg      [0, 32K)
//   counts   [32K, 64K)
//   doneCtr  [64K, 64K+4)        (zeroed with deg/counts)
//   cur      [96K, 128K)         (init by scan phase)
//   dinv     [128K, 160K)
//   rowstart [160K, 196K)        8193 ints
//   colw     [256K, 256K+2M)
//   V2       [4M, 4M+512K)

// ---------------- zero deg + counts + doneCtr ----------------
__global__ void zero_kernel(int* __restrict__ p) {
    int i = blockIdx.x * blockDim.x + threadIdx.x;   // 20480 words = 80 KB
    p[i] = 0;
}

// ---------------- histogram + weighted degree, last block scans ----------------
__global__ __launch_bounds__(256) void hist_scan_kernel(const int* __restrict__ ei,
                                                        const float* __restrict__ ew,
                                                        float* __restrict__ deg,
                                                        int* __restrict__ counts,
                                                        int* __restrict__ doneCtr,
                                                        int* __restrict__ rowstart,
                                                        int* __restrict__ cur,
                                                        float* __restrict__ dinv) {
    __shared__ int isLast;
    __shared__ int wsum[4];
    __shared__ int woff[4];
    int t = threadIdx.x;
    int e = blockIdx.x * 256 + t;        // grid = 1024 * 256 = E exactly
    int r = ei[e];
    atomicAdd(&deg[r], ew[e]);
    atomicAdd(&counts[r], 1);
    __threadfence();
    __syncthreads();
    if (t == 0) {
        int old = atomicAdd(doneCtr, 1);
        isLast = (old == (int)gridDim.x - 1);
    }
    __syncthreads();
    if (!isLast) return;

    // ---- scan phase: 256 threads, 32 rows each. Read counts/deg via
    // device-scope atomic reads (cross-XCD coherent point). ----
    int base = t * 32;
    int vals[32];
    int s = 0;
    #pragma unroll
    for (int i = 0; i < 32; ++i) {
        vals[i] = s;
        s += atomicAdd(&counts[base + i], 0);
        float d = atomicAdd(&deg[base + i], 0.0f) + 1.0f;  // + self loop, >= 1
        dinv[base + i] = 1.0f / sqrtf(d);
    }
    int lane = t & 63, wave = t >> 6;
    int sc = s;  // inclusive wave scan of per-thread totals
    #pragma unroll
    for (int off = 1; off < 64; off <<= 1) {
        int u = __shfl_up(sc, off);
        if (lane >= off) sc += u;
    }
    if (lane == 63) wsum[wave] = sc;
    __syncthreads();
    if (t == 0) { int a = 0; for (int i = 0; i < 4; ++i) { woff[i] = a; a += wsum[i]; } }
    __syncthreads();
    int texcl = sc - s + woff[wave];
    #pragma unroll
    for (int i = 0; i < 32; ++i) {
        int v = texcl + vals[i];
        rowstart[base + i] = v;
        cur[base + i] = v;
    }
    if (t == 255) rowstart[N_NODES] = texcl + s;   // == E
}

// ---------------- scatter edges into CSR order, weight pre-normalized ----------------
__global__ void scatter_kernel(const int* __restrict__ ei, const float* __restrict__ ew,
                               const float* __restrict__ dinv,
                               int* __restrict__ cur, int2* __restrict__ colw, int E) {
    int e = blockIdx.x * blockDim.x + threadIdx.x;
    if (e < E) {
        int r = ei[e];
        int c = ei[E + e];
        int pos = atomicAdd(&cur[r], 1);
        float w = ew[e] * dinv[r] * dinv[c];
        colw[pos] = make_int2(c, __float_as_int(w));
    }
}

// ---------------- fused: AX-tile (gather) -> H = relu(AX@W1+b1) -> V2 = H@W2 ----------------
// 8 rows per block, 1024 blocks.
__global__ __launch_bounds__(256) void layer12_kernel(const int* __restrict__ rowstart,
                                                      const int2* __restrict__ colw,
                                                      const float* __restrict__ x,
                                                      const float* __restrict__ dinv,
                                                      const float* __restrict__ W1,
                                                      const float* __restrict__ b1,
                                                      const float* __restrict__ W2,
                                                      float* __restrict__ V2) {
    __shared__ float axs[8][NFEAT];       // 4 KB
    __shared__ float hs[8][NHID];         // 8 KB
    __shared__ float w2s[NHID * NCLASS];  // 16 KB
    __shared__ float part[256];           // 1 KB
    int t = threadIdx.x;

    // stage W2 (independent of gather)
    #pragma unroll
    for (int i = 0; i < 16; ++i) w2s[i * 256 + t] = W2[i * 256 + t];

    // ---- phase A: AX[r] = dinv[r]^2 x[r] + sum w' x[c]; 32 lanes/row, float4/lane
    int lane = t & 31;
    int rloc = t >> 5;
    int r = blockIdx.x * 8 + rloc;
    int s = rowstart[r], e = rowstart[r + 1];
    const float4* x4 = (const float4*)x;
    float di = dinv[r];
    float c0 = di * di;
    float4 xv = x4[r * 32 + lane];
    float4 acc;
    acc.x = c0 * xv.x; acc.y = c0 * xv.y; acc.z = c0 * xv.z; acc.w = c0 * xv.w;
    for (int base = s; base < e; base += 32) {
        int kk = base + lane;
        int2 cw = colw[kk < e ? kk : s];   // lanes past end read a valid dummy
        int m = min(32, e - base);
        for (int u = 0; u < m; ++u) {
            int c = __shfl(cw.x, u, 32);
            float w = __int_as_float(__shfl(cw.y, u, 32));
            float4 v = x4[c * 32 + lane];
            acc.x += w * v.x; acc.y += w * v.y; acc.z += w * v.z; acc.w += w * v.w;
        }
    }
    ((float4*)&axs[rloc][0])[lane] = acc;
    __syncthreads();

    // ---- phase B: hs[r][t] = relu(sum_k axs[r][k] * W1[k][t] + b1[t]); t = column
    float hacc[8];
    #pragma unroll
    for (int q = 0; q < 8; ++q) hacc[q] = 0.0f;
    #pragma unroll 4
    for (int k = 0; k < NFEAT; ++k) {
        float w = W1[k * NHID + t];
        #pragma unroll
        for (int q = 0; q < 8; ++q) hacc[q] += axs[q][k] * w;
    }
    float bb = b1[t];
    #pragma unroll
    for (int q = 0; q < 8; ++q) {
        float v = hacc[q] + bb;
        hs[q][t] = v > 0.0f ? v : 0.0f;
    }
    __syncthreads();

    // ---- phase C: V2[r][j] = sum_k hs[r][k] * w2s[k][j]; split k in halves
    int j = t & 15;
    int rq = (t >> 4) & 7;
    int kb = (t >> 7) * 128;
    float p = 0.0f;
    #pragma unroll 8
    for (int k = 0; k < 128; ++k) p += hs[rq][kb + k] * w2s[(kb + k) * NCLASS + j];
    part[t] = p;
    __syncthreads();
    if (t < 128) {
        int rg = blockIdx.x * 8 + (t >> 4);
        V2[rg * NCLASS + (t & 15)] = part[t] + part[t + 128];
    }
}

// ---------------- out[r] = log_softmax(dinv[r]^2*V2[r] + sum w'*V2[c] + b2) ----------------
__global__ __launch_bounds__(256) void agg2_kernel(const int* __restrict__ rowstart,
                                                   const int2* __restrict__ colw,
                                                   const float* __restrict__ V2,
                                                   const float* __restrict__ dinv,
                                                   const float* __restrict__ b2,
                                                   float* __restrict__ out) {
    int t = threadIdx.x;
    int j = t & 15;                   // class
    int r = blockIdx.x * 16 + (t >> 4);
    int s = rowstart[r], e = rowstart[r + 1];
    float di = dinv[r];
    float acc = di * di * V2[r * NCLASS + j];
    for (int base = s; base < e; base += 16) {
        int kk = base + j;
        int2 cw = colw[kk < e ? kk : s];
        int m = min(16, e - base);
        for (int u = 0; u < m; ++u) {
            int c = __shfl(cw.x, u, 16);
            float w = __int_as_float(__shfl(cw.y, u, 16));
            acc += w * V2[c * NCLASS + j];
        }
    }
    float v = acc + b2[j];
    // log_softmax across the 16 lanes of this row-group
    float mx = v;
    #pragma unroll
    for (int off = 1; off < 16; off <<= 1) mx = fmaxf(mx, __shfl_xor(mx, off));
    float ex = expf(v - mx);
    float ssum = ex;
    #pragma unroll
    for (int off = 1; off < 16; off <<= 1) ssum += __shfl_xor(ssum, off);
    out[r * NCLASS + j] = v - mx - logf(ssum);
}

extern "C" void kernel_launch(void* const* d_in, const int* in_sizes, int n_in,
                              void* d_out, int out_size, void* d_ws, size_t ws_size,
                              hipStream_t stream) {
    const float* x  = (const float*)d_in[0];
    const int*   ei = (const int*)d_in[1];      // [2, E] flat: row = ei[e], col = ei[E+e]
    const float* ew = (const float*)d_in[2];
    const float* W1 = (const float*)d_in[3];
    const float* b1 = (const float*)d_in[4];
    const float* W2 = (const float*)d_in[5];
    const float* b2 = (const float*)d_in[6];
    float* out = (float*)d_out;

    const int E = N_EDGES;
    const int n = N_NODES;

    char* ws = (char*)d_ws;
    float* deg      = (float*)(ws);                       // [0, 32K)
    int*   counts   = (int*)  (ws + 32768);               // [32K, 64K)
    int*   doneCtr  = (int*)  (ws + 65536);               // [64K, 64K+4)
    int*   cur      = (int*)  (ws + 98304);               // [96K, 128K)
    float* dinv     = (float*)(ws + 131072);              // [128K, 160K)
    int*   rowstart = (int*)  (ws + 163840);              // [160K, 196K): 8193 ints
    int2*  colw     = (int2*) (ws + 262144);              // [256K, 256K+2M)
    float* V2       = (float*)(ws + 4194304);             // [4M, 4M+512K)

    zero_kernel<<<80, 256, 0, stream>>>((int*)ws);  // deg + counts + doneCtr

    hist_scan_kernel<<<E / 256, 256, 0, stream>>>(ei, ew, deg, counts, doneCtr,
                                                  rowstart, cur, dinv);
    scatter_kernel<<<E / 256, 256, 0, stream>>>(ei, ew, dinv, cur, colw, E);

    layer12_kernel<<<n / 8, 256, 0, stream>>>(rowstart, colw, x, dinv, W1, b1, W2, V2);
    agg2_kernel<<<n / 16, 256, 0, stream>>>(rowstart, colw, V2, dinv, b2, out);
}

// Round 7
// 93.319 us; speedup vs baseline: 1.7107x; 1.7107x over previous
//
#include <hip/hip_runtime.h>
#include <math.h>

#define N_NODES 8192
#define N_EDGES 262144
#define NFEAT 128
#define NHID 256
#define NCLASS 16

// ---------------- zero deg + counts (contiguous 64 KB) ----------------
__global__ void zero_kernel(int* __restrict__ p) {
    int i = blockIdx.x * blockDim.x + threadIdx.x;   // 16384 words
    p[i] = 0;
}

// ---------------- histogram + weighted degree ----------------
__global__ void hist_deg_kernel(const int* __restrict__ ei, const float* __restrict__ ew,
                                float* __restrict__ deg, int* __restrict__ counts, int E) {
    int e = blockIdx.x * blockDim.x + threadIdx.x;
    if (e < E) {
        int r = ei[e];
        atomicAdd(&deg[r], ew[e]);
        atomicAdd(&counts[r], 1);
    }
}

// ---------------- exclusive prefix scan of counts + dinv (single block) ----------------
// Separate launch => plain cached loads of counts/deg are coherent. (Round-6
// lesson: single-block bulk atomic reads = ~80 us of serialized latency.)
__global__ __launch_bounds__(1024) void scan_kernel(const int* __restrict__ counts,
                                                    const float* __restrict__ deg,
                                                    int* __restrict__ rowstart,
                                                    int* __restrict__ cur,
                                                    float* __restrict__ dinv) {
    __shared__ int wsum[16];
    __shared__ int woff[16];
    int t = threadIdx.x;              // 0..1023, each handles 8 rows
    int base = t * 8;
    int vals[8];
    int s = 0;
    #pragma unroll
    for (int i = 0; i < 8; ++i) {
        vals[i] = s; s += counts[base + i];
        float d = deg[base + i] + 1.0f;            // + self loop, always >= 1
        dinv[base + i] = 1.0f / sqrtf(d);
    }
    int lane = t & 63, wave = t >> 6;
    int sc = s;  // inclusive wave scan of per-thread totals
    #pragma unroll
    for (int off = 1; off < 64; off <<= 1) {
        int u = __shfl_up(sc, off);
        if (lane >= off) sc += u;
    }
    if (lane == 63) wsum[wave] = sc;
    __syncthreads();
    if (t == 0) { int a = 0; for (int i = 0; i < 16; ++i) { woff[i] = a; a += wsum[i]; } }
    __syncthreads();
    int texcl = sc - s + woff[wave];
    #pragma unroll
    for (int i = 0; i < 8; ++i) {
        int v = texcl + vals[i];
        rowstart[base + i] = v;
        cur[base + i] = v;            // scatter's running cursor starts at rowstart
    }
    if (t == 1023) rowstart[N_NODES] = texcl + s;  // == E
}

// ---------------- scatter edges into CSR order, weight pre-normalized ----------------
// w' = w * dinv[r] * dinv[c]; packed with col into one 8B store.
__global__ void scatter_kernel(const int* __restrict__ ei, const float* __restrict__ ew,
                               const float* __restrict__ dinv,
                               int* __restrict__ cur, int2* __restrict__ colw, int E) {
    int e = blockIdx.x * blockDim.x + threadIdx.x;
    if (e < E) {
        int r = ei[e];
        int c = ei[E + e];
        int pos = atomicAdd(&cur[r], 1);
        float w = ew[e] * dinv[r] * dinv[c];
        colw[pos] = make_int2(c, __float_as_int(w));
    }
}

// ---------------- fused: AX-tile (gather) -> H = relu(AX@W1+b1) -> V2 = H@W2 ----------------
// 8 rows per block, 1024 blocks.
__global__ __launch_bounds__(256) void layer12_kernel(const int* __restrict__ rowstart,
                                                      const int2* __restrict__ colw,
                                                      const float* __restrict__ x,
                                                      const float* __restrict__ dinv,
                                                      const float* __restrict__ W1,
                                                      const float* __restrict__ b1,
                                                      const float* __restrict__ W2,
                                                      float* __restrict__ V2) {
    __shared__ float axs[8][NFEAT];       // 4 KB
    __shared__ float hs[8][NHID];         // 8 KB
    __shared__ float w2s[NHID * NCLASS];  // 16 KB
    __shared__ float part[256];           // 1 KB
    int t = threadIdx.x;

    // stage W2 (independent of gather)
    #pragma unroll
    for (int i = 0; i < 16; ++i) w2s[i * 256 + t] = W2[i * 256 + t];

    // ---- phase A: AX[r] = dinv[r]^2 x[r] + sum w' x[c]; 32 lanes/row, float4/lane
    int lane = t & 31;
    int rloc = t >> 5;
    int r = blockIdx.x * 8 + rloc;
    int s = rowstart[r], e = rowstart[r + 1];
    const float4* x4 = (const float4*)x;
    float di = dinv[r];
    float c0 = di * di;
    float4 xv = x4[r * 32 + lane];
    float4 acc;
    acc.x = c0 * xv.x; acc.y = c0 * xv.y; acc.z = c0 * xv.z; acc.w = c0 * xv.w;
    for (int base = s; base < e; base += 32) {
        int kk = base + lane;
        int2 cw = colw[kk < e ? kk : s];   // lanes past end read a valid dummy
        int m = min(32, e - base);
        for (int u = 0; u < m; ++u) {
            int c = __shfl(cw.x, u, 32);
            float w = __int_as_float(__shfl(cw.y, u, 32));
            float4 v = x4[c * 32 + lane];
            acc.x += w * v.x; acc.y += w * v.y; acc.z += w * v.z; acc.w += w * v.w;
        }
    }
    ((float4*)&axs[rloc][0])[lane] = acc;
    __syncthreads();

    // ---- phase B: hs[r][t] = relu(sum_k axs[r][k] * W1[k][t] + b1[t]); t = column
    float hacc[8];
    #pragma unroll
    for (int q = 0; q < 8; ++q) hacc[q] = 0.0f;
    #pragma unroll 4
    for (int k = 0; k < NFEAT; ++k) {
        float w = W1[k * NHID + t];
        #pragma unroll
        for (int q = 0; q < 8; ++q) hacc[q] += axs[q][k] * w;
    }
    float bb = b1[t];
    #pragma unroll
    for (int q = 0; q < 8; ++q) {
        float v = hacc[q] + bb;
        hs[q][t] = v > 0.0f ? v : 0.0f;
    }
    __syncthreads();

    // ---- phase C: V2[r][j] = sum_k hs[r][k] * w2s[k][j]; split k in halves
    int j = t & 15;
    int rq = (t >> 4) & 7;
    int kb = (t >> 7) * 128;
    float p = 0.0f;
    #pragma unroll 8
    for (int k = 0; k < 128; ++k) p += hs[rq][kb + k] * w2s[(kb + k) * NCLASS + j];
    part[t] = p;
    __syncthreads();
    if (t < 128) {
        int rg = blockIdx.x * 8 + (t >> 4);
        V2[rg * NCLASS + (t & 15)] = part[t] + part[t + 128];
    }
}

// ---------------- out[r] = log_softmax(dinv[r]^2*V2[r] + sum w'*V2[c] + b2) ----------------
__global__ __launch_bounds__(256) void agg2_kernel(const int* __restrict__ rowstart,
                                                   const int2* __restrict__ colw,
                                                   const float* __restrict__ V2,
                                                   const float* __restrict__ dinv,
                                                   const float* __restrict__ b2,
                                                   float* __restrict__ out) {
    int t = threadIdx.x;
    int j = t & 15;                   // class
    int r = blockIdx.x * 16 + (t >> 4);
    int s = rowstart[r], e = rowstart[r + 1];
    float di = dinv[r];
    float acc = di * di * V2[r * NCLASS + j];
    for (int base = s; base < e; base += 16) {
        int kk = base + j;
        int2 cw = colw[kk < e ? kk : s];
        int m = min(16, e - base);
        for (int u = 0; u < m; ++u) {
            int c = __shfl(cw.x, u, 16);
            float w = __int_as_float(__shfl(cw.y, u, 16));
            acc += w * V2[c * NCLASS + j];
        }
    }
    float v = acc + b2[j];
    // log_softmax across the 16 lanes of this row-group
    float mx = v;
    #pragma unroll
    for (int off = 1; off < 16; off <<= 1) mx = fmaxf(mx, __shfl_xor(mx, off));
    float ex = expf(v - mx);
    float ssum = ex;
    #pragma unroll
    for (int off = 1; off < 16; off <<= 1) ssum += __shfl_xor(ssum, off);
    out[r * NCLASS + j] = v - mx - logf(ssum);
}

extern "C" void kernel_launch(void* const* d_in, const int* in_sizes, int n_in,
                              void* d_out, int out_size, void* d_ws, size_t ws_size,
                              hipStream_t stream) {
    const float* x  = (const float*)d_in[0];
    const int*   ei = (const int*)d_in[1];      // [2, E] flat: row = ei[e], col = ei[E+e]
    const float* ew = (const float*)d_in[2];
    const float* W1 = (const float*)d_in[3];
    const float* b1 = (const float*)d_in[4];
    const float* W2 = (const float*)d_in[5];
    const float* b2 = (const float*)d_in[6];
    float* out = (float*)d_out;

    const int E = N_EDGES;
    const int n = N_NODES;

    char* ws = (char*)d_ws;
    float* deg      = (float*)(ws);                       // [0, 32K)
    int*   counts   = (int*)  (ws + 32768);               // [32K, 64K)
    int*   cur      = (int*)  (ws + 65536);               // [64K, 96K) (init by scan)
    float* dinv     = (float*)(ws + 98304);               // [96K, 128K)
    int*   rowstart = (int*)  (ws + 131072);              // [128K, 164K): 8193 ints + pad
    int2*  colw     = (int2*) (ws + 262144);              // [256K, 256K+2M)
    float* V2       = (float*)(ws + 4194304);             // [4M, 4M+512K)

    zero_kernel<<<64, 256, 0, stream>>>((int*)ws);  // deg + counts = 16384 words

    hist_deg_kernel<<<E / 256, 256, 0, stream>>>(ei, ew, deg, counts, E);
    scan_kernel<<<1, 1024, 0, stream>>>(counts, deg, rowstart, cur, dinv);
    scatter_kernel<<<E / 256, 256, 0, stream>>>(ei, ew, dinv, cur, colw, E);

    layer12_kernel<<<n / 8, 256, 0, stream>>>(rowstart, colw, x, dinv, W1, b1, W2, V2);
    agg2_kernel<<<n / 16, 256, 0, stream>>>(rowstart, colw, V2, dinv, b2, out);
}